// Round 1
// baseline (212.553 us; speedup 1.0000x reference)
//
#include <hip/hip_runtime.h>
#include <hip/hip_bf16.h>

// IDST (DST-III, x2) as y = x @ W, W[n][k] = 2*a_n*sin(pi*(n+1)*(2k+1)/(2N)).
// Strategy: f32->bf16 convert x, generate W^T (K-contiguous) in bf16 in d_ws,
// then m97-style 128x128 bf16 MFMA GEMM (global_load_lds width=16).
// ws usage: 32MB x_bf16 + 32MB Wt_bf16 = 64MB.

#define MDIM 4096
#define NDIM 4096
#define KDIM 4096

using f32x4  = __attribute__((ext_vector_type(4))) float;
using bf16x8 = __attribute__((ext_vector_type(8))) short;

__device__ inline unsigned short f2bf(float f) {
    union { float f; unsigned int u; } v; v.f = f;
    unsigned int r = (v.u + 0x7fffu + ((v.u >> 16) & 1u)) >> 16; // RNE
    return (unsigned short)r;
}

// x (f32, M*K) -> bf16. 8 elems/thread.
__global__ __launch_bounds__(256) void cvt_x_bf16(const float* __restrict__ x,
                                                  unsigned short* __restrict__ o) {
    int idx = blockIdx.x * 256 + threadIdx.x;
    const float4* xin = (const float4*)x;
    float4 a = xin[2 * idx];
    float4 b = xin[2 * idx + 1];
    union { unsigned short u[8]; uint4 v; } r;
    r.u[0] = f2bf(a.x); r.u[1] = f2bf(a.y); r.u[2] = f2bf(a.z); r.u[3] = f2bf(a.w);
    r.u[4] = f2bf(b.x); r.u[5] = f2bf(b.y); r.u[6] = f2bf(b.z); r.u[7] = f2bf(b.w);
    ((uint4*)o)[idx] = r.v;
}

// Wt[k][n] = 2*a_n*sin(pi*(n+1)*(2k+1)/8192), a_{N-1}=0.5. Row k = output col.
// Exact arg reduction: m = ((n+1)*(2k+1)) mod 16384, ang = m*pi/8192 in [0,2pi).
__global__ __launch_bounds__(256) void gen_Wt(unsigned short* __restrict__ Wt) {
    int idx = blockIdx.x * 256 + threadIdx.x;   // 8 elems/thread
    int k  = idx >> 9;                          // KDIM/8 = 512 chunks per row
    int n0 = (idx & 511) * 8;
    unsigned int tk = 2u * (unsigned)k + 1u;
    union { unsigned short u[8]; uint4 v; } r;
#pragma unroll
    for (int t = 0; t < 8; ++t) {
        unsigned int n = (unsigned)(n0 + t);
        unsigned int m = ((n + 1u) * tk) & 16383u;
        float ang = (float)m * 3.8349519697e-4f;   // pi/8192
        float s = __sinf(ang);
        float scale = (n == (unsigned)(KDIM - 1)) ? 1.0f : 2.0f;
        r.u[t] = f2bf(s * scale);
    }
    ((uint4*)Wt)[idx] = r.v;
}

// C[M][N] = A[M][K] * Wt[N][K]^T. 128x128 tile, BK=64, 4 waves (2x2),
// each wave 64x64 out = 4x4 grid of 16x16x32 MFMA fragments.
__global__ __launch_bounds__(256) void gemm_bt(const unsigned short* __restrict__ A,
                                               const unsigned short* __restrict__ Bt,
                                               float* __restrict__ C) {
    __shared__ unsigned short As[128 * 64];
    __shared__ unsigned short Bs[128 * 64];

    const int tid = threadIdx.x;
    const int w = tid >> 6;
    const int l = tid & 63;
    const int brow = blockIdx.y * 128;
    const int bcol = blockIdx.x * 128;
    const int wr = w >> 1, wc = w & 1;

    f32x4 acc[4][4];
#pragma unroll
    for (int m = 0; m < 4; ++m)
#pragma unroll
        for (int n = 0; n < 4; ++n) acc[m][n] = (f32x4){0.f, 0.f, 0.f, 0.f};

    const int srow = l >> 3;          // 0..7 within chunk
    const int scol = (l & 7) * 8;     // bf16 col offset

    for (int k0 = 0; k0 < KDIM; k0 += 64) {
        __syncthreads();
#pragma unroll
        for (int it = 0; it < 4; ++it) {
            int c = it * 4 + w;                   // chunk 0..15, 8 rows each
            int row = 8 * c + srow;
            __builtin_amdgcn_global_load_lds(
                (const __attribute__((address_space(1))) unsigned int*)
                    (A + (size_t)(brow + row) * KDIM + k0 + scol),
                (__attribute__((address_space(3))) unsigned int*)(As + c * 512),
                16, 0, 0);
            __builtin_amdgcn_global_load_lds(
                (const __attribute__((address_space(1))) unsigned int*)
                    (Bt + (size_t)(bcol + row) * KDIM + k0 + scol),
                (__attribute__((address_space(3))) unsigned int*)(Bs + c * 512),
                16, 0, 0);
        }
        __syncthreads();   // drains vmcnt -> LDS tiles ready

#pragma unroll
        for (int kk = 0; kk < 2; ++kk) {
            const int koff = kk * 32 + (l >> 4) * 8;
            bf16x8 af[4], bf[4];
#pragma unroll
            for (int m = 0; m < 4; ++m)
                af[m] = *(const bf16x8*)(As + (wr * 64 + m * 16 + (l & 15)) * 64 + koff);
#pragma unroll
            for (int n = 0; n < 4; ++n)
                bf[n] = *(const bf16x8*)(Bs + (wc * 64 + n * 16 + (l & 15)) * 64 + koff);
#pragma unroll
            for (int m = 0; m < 4; ++m)
#pragma unroll
                for (int n = 0; n < 4; ++n)
                    acc[m][n] = __builtin_amdgcn_mfma_f32_16x16x32_bf16(
                        af[m], bf[n], acc[m][n], 0, 0, 0);
        }
    }

    // C/D layout: col = lane&15, row = (lane>>4)*4 + reg
#pragma unroll
    for (int m = 0; m < 4; ++m) {
        int r0 = brow + wr * 64 + m * 16 + (l >> 4) * 4;
#pragma unroll
        for (int n = 0; n < 4; ++n) {
            int c0 = bcol + wc * 64 + n * 16 + (l & 15);
#pragma unroll
            for (int r = 0; r < 4; ++r)
                C[(size_t)(r0 + r) * NDIM + c0] = acc[m][n][r];
        }
    }
}

extern "C" void kernel_launch(void* const* d_in, const int* in_sizes, int n_in,
                              void* d_out, int out_size, void* d_ws, size_t ws_size,
                              hipStream_t stream) {
    const float* x = (const float*)d_in[0];
    // d_in[1] = expk — not needed; trig regenerated exactly on device.
    float* out = (float*)d_out;

    unsigned short* xb = (unsigned short*)d_ws;                  // 32 MB
    unsigned short* wt = xb + (size_t)MDIM * KDIM;               // 32 MB

    cvt_x_bf16<<<(MDIM * KDIM / 8) / 256, 256, 0, stream>>>(x, xb);
    gen_Wt<<<(NDIM * KDIM / 8) / 256, 256, 0, stream>>>(wt);

    dim3 grid(NDIM / 128, MDIM / 128);
    gemm_bt<<<grid, 256, 0, stream>>>(xb, wt, out);
}

// Round 2
// 183.015 us; speedup vs baseline: 1.1614x; 1.1614x over previous
//
#include <hip/hip_runtime.h>
#include <hip/hip_bf16.h>

// IDST (DST-III, x2) as y = x @ W, W[n][k] = 2*a_n*sin(pi*(n+1)*(2k+1)/(2N)).
// R2: fix 16-way LDS bank conflicts (5.0e7 measured) via both-sides XOR swizzle
// (rule #21): linear gload_lds dest + inverse-swizzled global SOURCE slot +
// swizzled ds_read address. slot ^= (row&7).

#define MDIM 4096
#define NDIM 4096
#define KDIM 4096

using f32x4  = __attribute__((ext_vector_type(4))) float;
using bf16x8 = __attribute__((ext_vector_type(8))) short;

__device__ inline unsigned short f2bf(float f) {
    union { float f; unsigned int u; } v; v.f = f;
    unsigned int r = (v.u + 0x7fffu + ((v.u >> 16) & 1u)) >> 16; // RNE
    return (unsigned short)r;
}

// x (f32, M*K) -> bf16. 8 elems/thread.
__global__ __launch_bounds__(256) void cvt_x_bf16(const float* __restrict__ x,
                                                  unsigned short* __restrict__ o) {
    int idx = blockIdx.x * 256 + threadIdx.x;
    const float4* xin = (const float4*)x;
    float4 a = xin[2 * idx];
    float4 b = xin[2 * idx + 1];
    union { unsigned short u[8]; uint4 v; } r;
    r.u[0] = f2bf(a.x); r.u[1] = f2bf(a.y); r.u[2] = f2bf(a.z); r.u[3] = f2bf(a.w);
    r.u[4] = f2bf(b.x); r.u[5] = f2bf(b.y); r.u[6] = f2bf(b.z); r.u[7] = f2bf(b.w);
    ((uint4*)o)[idx] = r.v;
}

// Wt[k][n] = 2*a_n*sin(pi*(n+1)*(2k+1)/8192), a_{N-1}=0.5. Row k = output col.
__global__ __launch_bounds__(256) void gen_Wt(unsigned short* __restrict__ Wt) {
    int idx = blockIdx.x * 256 + threadIdx.x;   // 8 elems/thread
    int k  = idx >> 9;
    int n0 = (idx & 511) * 8;
    unsigned int tk = 2u * (unsigned)k + 1u;
    union { unsigned short u[8]; uint4 v; } r;
#pragma unroll
    for (int t = 0; t < 8; ++t) {
        unsigned int n = (unsigned)(n0 + t);
        unsigned int m = ((n + 1u) * tk) & 16383u;
        float ang = (float)m * 3.8349519697e-4f;   // pi/8192
        float s = __sinf(ang);
        float scale = (n == (unsigned)(KDIM - 1)) ? 1.0f : 2.0f;
        r.u[t] = f2bf(s * scale);
    }
    ((uint4*)Wt)[idx] = r.v;
}

// C[M][N] = A[M][K] * Wt[N][K]^T. 128x128 tile, BK=64, 4 waves (2x2).
// LDS layout (both A and B): stored[row][s] = data[row][s ^ (row&7)] where
// s = 16B slot index 0..7 within a 128B row. Achieved by pre-swizzling the
// global source slot in the gload_lds staging (LDS dest stays linear).
__global__ __launch_bounds__(256) void gemm_bt(const unsigned short* __restrict__ A,
                                               const unsigned short* __restrict__ Bt,
                                               float* __restrict__ C) {
    __shared__ unsigned short As[128 * 64];
    __shared__ unsigned short Bs[128 * 64];

    const int tid = threadIdx.x;
    const int w = tid >> 6;
    const int l = tid & 63;
    const int brow = blockIdx.y * 128;
    const int bcol = blockIdx.x * 128;
    const int wr = w >> 1, wc = w & 1;

    f32x4 acc[4][4];
#pragma unroll
    for (int m = 0; m < 4; ++m)
#pragma unroll
        for (int n = 0; n < 4; ++n) acc[m][n] = (f32x4){0.f, 0.f, 0.f, 0.f};

    const int srow = l >> 3;                       // row within 8-row chunk
    const int sslot = (l & 7) ^ (srow & 7);        // swizzled global 16B slot
    const int scol = sslot * 8;                    // bf16 col offset in source

    const int rl = l & 15;                         // fragment row within 16
    const int g  = l >> 4;                         // k-group 0..3

    for (int k0 = 0; k0 < KDIM; k0 += 64) {
        __syncthreads();
#pragma unroll
        for (int it = 0; it < 4; ++it) {
            int c = it * 4 + w;                    // chunk 0..15, 8 rows each
            int row = 8 * c + srow;
            __builtin_amdgcn_global_load_lds(
                (const __attribute__((address_space(1))) unsigned int*)
                    (A + (size_t)(brow + row) * KDIM + k0 + scol),
                (__attribute__((address_space(3))) unsigned int*)(As + c * 512),
                16, 0, 0);
            __builtin_amdgcn_global_load_lds(
                (const __attribute__((address_space(1))) unsigned int*)
                    (Bt + (size_t)(bcol + row) * KDIM + k0 + scol),
                (__attribute__((address_space(3))) unsigned int*)(Bs + c * 512),
                16, 0, 0);
        }
        __syncthreads();   // drains vmcnt -> LDS tiles ready

#pragma unroll
        for (int kk = 0; kk < 2; ++kk) {
            const int cslot = kk * 4 + g;          // logical 16B slot (k-chunk)
            bf16x8 af[4], bfr[4];
#pragma unroll
            for (int m = 0; m < 4; ++m) {
                int r = wr * 64 + m * 16 + rl;
                af[m] = *(const bf16x8*)(As + r * 64 + ((cslot ^ (r & 7)) * 8));
            }
#pragma unroll
            for (int n = 0; n < 4; ++n) {
                int r = wc * 64 + n * 16 + rl;
                bfr[n] = *(const bf16x8*)(Bs + r * 64 + ((cslot ^ (r & 7)) * 8));
            }
#pragma unroll
            for (int m = 0; m < 4; ++m)
#pragma unroll
                for (int n = 0; n < 4; ++n)
                    acc[m][n] = __builtin_amdgcn_mfma_f32_16x16x32_bf16(
                        af[m], bfr[n], acc[m][n], 0, 0, 0);
        }
    }

    // C/D layout: col = lane&15, row = (lane>>4)*4 + reg
#pragma unroll
    for (int m = 0; m < 4; ++m) {
        int r0 = brow + wr * 64 + m * 16 + (l >> 4) * 4;
#pragma unroll
        for (int n = 0; n < 4; ++n) {
            int c0 = bcol + wc * 64 + n * 16 + (l & 15);
#pragma unroll
            for (int r = 0; r < 4; ++r)
                C[(size_t)(r0 + r) * NDIM + c0] = acc[m][n][r];
        }
    }
}

extern "C" void kernel_launch(void* const* d_in, const int* in_sizes, int n_in,
                              void* d_out, int out_size, void* d_ws, size_t ws_size,
                              hipStream_t stream) {
    const float* x = (const float*)d_in[0];
    float* out = (float*)d_out;

    unsigned short* xb = (unsigned short*)d_ws;                  // 32 MB
    unsigned short* wt = xb + (size_t)MDIM * KDIM;               // 32 MB

    cvt_x_bf16<<<(MDIM * KDIM / 8) / 256, 256, 0, stream>>>(x, xb);
    gen_Wt<<<(NDIM * KDIM / 8) / 256, 256, 0, stream>>>(wt);

    dim3 grid(NDIM / 128, MDIM / 128);
    gemm_bt<<<grid, 256, 0, stream>>>(xb, wt, out);
}

// Round 3
// 135.945 us; speedup vs baseline: 1.5635x; 1.3462x over previous
//
#include <hip/hip_runtime.h>
#include <hip/hip_bf16.h>

// IDST (DST-III, x2) as y = x @ W, W[n][k] = 2*a_n*sin(pi*(n+1)*(2k+1)/(2N)).
// R3: 256x256-tile 8-phase GEMM (T2 swizzle + T3/T4 counted-vmcnt + T5 setprio).
// 512 thr / 8 waves (2x4), per-wave 128x64, BK=64, LDS 128 KiB double-buffered.

#define MDIM 4096
#define NDIM 4096
#define KDIM 4096
#define NKT  (KDIM / 64)

using f32x4  = __attribute__((ext_vector_type(4))) float;
using bf16x8 = __attribute__((ext_vector_type(8))) short;

__device__ inline unsigned short f2bf(float f) {
    union { float f; unsigned int u; } v; v.f = f;
    unsigned int r = (v.u + 0x7fffu + ((v.u >> 16) & 1u)) >> 16; // RNE
    return (unsigned short)r;
}

__global__ __launch_bounds__(256) void cvt_x_bf16(const float* __restrict__ x,
                                                  unsigned short* __restrict__ o) {
    int idx = blockIdx.x * 256 + threadIdx.x;
    const float4* xin = (const float4*)x;
    float4 a = xin[2 * idx];
    float4 b = xin[2 * idx + 1];
    union { unsigned short u[8]; uint4 v; } r;
    r.u[0] = f2bf(a.x); r.u[1] = f2bf(a.y); r.u[2] = f2bf(a.z); r.u[3] = f2bf(a.w);
    r.u[4] = f2bf(b.x); r.u[5] = f2bf(b.y); r.u[6] = f2bf(b.z); r.u[7] = f2bf(b.w);
    ((uint4*)o)[idx] = r.v;
}

__global__ __launch_bounds__(256) void gen_Wt(unsigned short* __restrict__ Wt) {
    int idx = blockIdx.x * 256 + threadIdx.x;
    int k  = idx >> 9;
    int n0 = (idx & 511) * 8;
    unsigned int tk = 2u * (unsigned)k + 1u;
    union { unsigned short u[8]; uint4 v; } r;
#pragma unroll
    for (int t = 0; t < 8; ++t) {
        unsigned int n = (unsigned)(n0 + t);
        unsigned int m = ((n + 1u) * tk) & 16383u;
        float ang = (float)m * 3.8349519697e-4f;   // pi/8192
        float s = __sinf(ang);
        float scale = (n == (unsigned)(KDIM - 1)) ? 1.0f : 2.0f;
        r.u[t] = f2bf(s * scale);
    }
    ((uint4*)Wt)[idx] = r.v;
}

// Stage one 128-row x 64-col half-tile: 2 gload_lds/thread, linear LDS dest,
// pre-swizzled global source (slot ^= row&7) -> zero-conflict ds_read later.
__device__ __forceinline__ void stage_half(const unsigned short* __restrict__ G,
                                           int grow, int kbase,
                                           unsigned short* lds, int w, int l) {
#pragma unroll
    for (int j = 0; j < 2; ++j) {
        int rh   = j * 64 + w * 8 + (l >> 3);
        int scol = ((l & 7) ^ (rh & 7)) * 8;
        __builtin_amdgcn_global_load_lds(
            (const __attribute__((address_space(1))) unsigned int*)
                (G + (size_t)(grow + rh) * KDIM + kbase + scol),
            (__attribute__((address_space(3))) unsigned int*)
                (lds + (j * 64 + w * 8) * 64),
            16, 0, 0);
    }
}

template <int MH, int NH>
__device__ __forceinline__ void do_mfma(f32x4 (&acc)[8][4], bf16x8 (&af)[4][2],
                                        bf16x8 (&bf)[2][2][2]) {
#pragma unroll
    for (int m = 0; m < 4; ++m)
#pragma unroll
        for (int n = 0; n < 2; ++n)
#pragma unroll
            for (int kk = 0; kk < 2; ++kk)
                acc[MH * 4 + m][NH * 2 + n] =
                    __builtin_amdgcn_mfma_f32_16x16x32_bf16(
                        af[m][kk], bf[NH][n][kk], acc[MH * 4 + m][NH * 2 + n],
                        0, 0, 0);
}

__global__ __launch_bounds__(512, 2) void gemm_bt(const unsigned short* __restrict__ A,
                                                  const unsigned short* __restrict__ Bt,
                                                  float* __restrict__ C) {
    __shared__ unsigned short LDS[4 * 256 * 64];   // 128 KiB
    unsigned short* const as0 = LDS;
    unsigned short* const as1 = LDS + 16384;
    unsigned short* const bs0 = LDS + 32768;
    unsigned short* const bs1 = LDS + 49152;

    const int tid = threadIdx.x;
    const int w = tid >> 6, l = tid & 63;
    const int wr = w >> 2, wc = w & 3;
    const int brow = blockIdx.y * 256, bcol = blockIdx.x * 256;

    const int rl = l & 15, g = l >> 4;
    const int aoff  = (wr * 128 + rl) * 64;
    const int boff  = (wc * 64 + rl) * 64;
    const int k0off = ((g)     ^ (rl & 7)) * 8;
    const int k1off = ((4 + g) ^ (rl & 7)) * 8;

    f32x4 acc[8][4];
#pragma unroll
    for (int m = 0; m < 8; ++m)
#pragma unroll
        for (int n = 0; n < 4; ++n) acc[m][n] = (f32x4){0.f, 0.f, 0.f, 0.f};

    bf16x8 af[4][2];
    bf16x8 bf[2][2][2];

#define RD_A(pa, mh)                                                          \
    _Pragma("unroll") for (int m = 0; m < 4; ++m) {                           \
        af[m][0] = *(const bf16x8*)((pa) + aoff + ((mh) * 64 + m * 16) * 64 + k0off); \
        af[m][1] = *(const bf16x8*)((pa) + aoff + ((mh) * 64 + m * 16) * 64 + k1off); \
    }
#define RD_B(pb, nh)                                                          \
    _Pragma("unroll") for (int n = 0; n < 2; ++n) {                           \
        bf[nh][n][0] = *(const bf16x8*)((pb) + boff + ((nh) * 32 + n * 16) * 64 + k0off); \
        bf[nh][n][1] = *(const bf16x8*)((pb) + boff + ((nh) * 32 + n * 16) * 64 + k1off); \
    }

#define KB(t) ((((t) & (NKT - 1))) * 64)

#define PH_TAIL(MH, NH)                                                       \
    __builtin_amdgcn_s_barrier();                                             \
    asm volatile("s_waitcnt lgkmcnt(0)" ::: "memory");                        \
    __builtin_amdgcn_s_setprio(1);                                            \
    do_mfma<MH, NH>(acc, af, bf);                                             \
    __builtin_amdgcn_s_setprio(0);                                            \
    __builtin_amdgcn_s_barrier();

    // Prologue: tile0 fully + tile1.A0; wait all but newest half.
    stage_half(A,  brow +   0, 0,  as0,             w, l);   // T0.A0
    stage_half(A,  brow + 128, 0,  as0 + 128 * 64,  w, l);   // T0.A1
    stage_half(Bt, bcol +   0, 0,  bs0,             w, l);   // T0.B0
    stage_half(Bt, bcol + 128, 0,  bs0 + 128 * 64,  w, l);   // T0.B1
    stage_half(A,  brow +   0, 64, as1,             w, l);   // T1.A0
    asm volatile("s_waitcnt vmcnt(2)" ::: "memory");
    __builtin_amdgcn_s_barrier();

    for (int it = 0; it < NKT / 2; ++it) {
        const int t2 = 2 * it;

        // ---- tile t2 (buf0) ----
        // P1: q(0,0); stage T+1.A1
        RD_A(as0, 0); RD_B(bs0, 0);
        stage_half(A, brow + 128, KB(t2 + 1), as1 + 128 * 64, w, l);
        PH_TAIL(0, 0)
        // P2: q(0,1); stage T+1.B0
        RD_B(bs0, 1);
        stage_half(Bt, bcol + 0, KB(t2 + 1), bs1, w, l);
        PH_TAIL(0, 1)
        // P3: q(1,1); stage T+1.B1
        RD_A(as0, 1);
        stage_half(Bt, bcol + 128, KB(t2 + 1), bs1 + 128 * 64, w, l);
        PH_TAIL(1, 1)
        // P4: q(1,0) (reuses bf[0] regs from P1); stage T+2.A0; counted wait
        stage_half(A, brow + 0, KB(t2 + 2), as0, w, l);
        asm volatile("s_waitcnt vmcnt(2)" ::: "memory");
        PH_TAIL(1, 0)

        // ---- tile t2+1 (buf1) ----
        // P5: q(0,0); stage T+2.A1
        RD_A(as1, 0); RD_B(bs1, 0);
        stage_half(A, brow + 128, KB(t2 + 2), as0 + 128 * 64, w, l);
        PH_TAIL(0, 0)
        // P6: q(0,1); stage T+2.B0
        RD_B(bs1, 1);
        stage_half(Bt, bcol + 0, KB(t2 + 2), bs0, w, l);
        PH_TAIL(0, 1)
        // P7: q(1,1); stage T+2.B1
        RD_A(as1, 1);
        stage_half(Bt, bcol + 128, KB(t2 + 2), bs0 + 128 * 64, w, l);
        PH_TAIL(1, 1)
        // P8: q(1,0); stage T+3.A0; counted wait
        stage_half(A, brow + 0, KB(t2 + 3), as1, w, l);
        asm volatile("s_waitcnt vmcnt(2)" ::: "memory");
        PH_TAIL(1, 0)
    }

    asm volatile("s_waitcnt vmcnt(0) lgkmcnt(0)" ::: "memory");

    // C/D layout: col = lane&15, row = (lane>>4)*4 + reg
#pragma unroll
    for (int m = 0; m < 8; ++m) {
        int r0 = brow + wr * 128 + m * 16 + (l >> 4) * 4;
#pragma unroll
        for (int n = 0; n < 4; ++n) {
            int c0 = bcol + wc * 64 + n * 16 + rl;
#pragma unroll
            for (int r = 0; r < 4; ++r)
                C[(size_t)(r0 + r) * NDIM + c0] = acc[m][n][r];
        }
    }
#undef RD_A
#undef RD_B
#undef KB
#undef PH_TAIL
}

extern "C" void kernel_launch(void* const* d_in, const int* in_sizes, int n_in,
                              void* d_out, int out_size, void* d_ws, size_t ws_size,
                              hipStream_t stream) {
    const float* x = (const float*)d_in[0];
    float* out = (float*)d_out;

    unsigned short* xb = (unsigned short*)d_ws;                  // 32 MB
    unsigned short* wt = xb + (size_t)MDIM * KDIM;               // 32 MB

    cvt_x_bf16<<<(MDIM * KDIM / 8) / 256, 256, 0, stream>>>(x, xb);
    gen_Wt<<<(NDIM * KDIM / 8) / 256, 256, 0, stream>>>(wt);

    dim3 grid(NDIM / 256, MDIM / 256);
    gemm_bt<<<grid, 512, 0, stream>>>(xb, wt, out);
}

// Round 4
// 135.237 us; speedup vs baseline: 1.5717x; 1.0052x over previous
//
#include <hip/hip_runtime.h>
#include <hip/hip_bf16.h>

// IDST (DST-III, x2) as y = x @ W, W[n][k] = 2*a_n*sin(pi*(n+1)*(2k+1)/(2N)).
// R4: deepen pipeline to m201 depth. Staging unit = interleaved quarter
// (Ae/Ao/Be/Bo) matching quadrant-read row-sets, so tile T+2 streams into the
// buffer being read. vmcnt(6) at P4/P8 = 3 half-tiles in flight (3-phase
// latency cover, was 1 phase in R3).

#define MDIM 4096
#define NDIM 4096
#define KDIM 4096
#define NKT  (KDIM / 64)

using f32x4  = __attribute__((ext_vector_type(4))) float;
using bf16x8 = __attribute__((ext_vector_type(8))) short;

__device__ inline unsigned short f2bf(float f) {
    union { float f; unsigned int u; } v; v.f = f;
    unsigned int r = (v.u + 0x7fffu + ((v.u >> 16) & 1u)) >> 16; // RNE
    return (unsigned short)r;
}

__global__ __launch_bounds__(256) void cvt_x_bf16(const float* __restrict__ x,
                                                  unsigned short* __restrict__ o) {
    int idx = blockIdx.x * 256 + threadIdx.x;
    const float4* xin = (const float4*)x;
    float4 a = xin[2 * idx];
    float4 b = xin[2 * idx + 1];
    union { unsigned short u[8]; uint4 v; } r;
    r.u[0] = f2bf(a.x); r.u[1] = f2bf(a.y); r.u[2] = f2bf(a.z); r.u[3] = f2bf(a.w);
    r.u[4] = f2bf(b.x); r.u[5] = f2bf(b.y); r.u[6] = f2bf(b.z); r.u[7] = f2bf(b.w);
    ((uint4*)o)[idx] = r.v;
}

__global__ __launch_bounds__(256) void gen_Wt(unsigned short* __restrict__ Wt) {
    int idx = blockIdx.x * 256 + threadIdx.x;
    int k  = idx >> 9;
    int n0 = (idx & 511) * 8;
    unsigned int tk = 2u * (unsigned)k + 1u;
    union { unsigned short u[8]; uint4 v; } r;
#pragma unroll
    for (int t = 0; t < 8; ++t) {
        unsigned int n = (unsigned)(n0 + t);
        unsigned int m = ((n + 1u) * tk) & 16383u;
        float ang = (float)m * 3.8349519697e-4f;   // pi/8192
        float s = __sinf(ang);
        float scale = (n == (unsigned)(KDIM - 1)) ? 1.0f : 2.0f;
        r.u[t] = f2bf(s * scale);
    }
    ((uint4*)Wt)[idx] = r.v;
}

// Stage one quarter-tile (64 rows as 16 x 8-row groups), 2 gload_lds/thread.
// SEL row-group map (base8 = row/8):
//   Ae: {0-7,16-23}   rows {0-63,128-191}    (freed by q(*,*) mh=0 reads, P1)
//   Ao: +8            rows {64-127,192-255}  (freed P3)
//   Be: {0-3,8-11,16-19,24-27} rows {0-31,64-95,128-159,192-223} (freed P1)
//   Bo: +4            (freed P2)
// Linear LDS dest per 8-row group; global source slot pre-swizzled (^row&7).
template <int SEL>
__device__ __forceinline__ void stage_part(const unsigned short* __restrict__ G,
                                           int growbase, int kbase,
                                           unsigned short* lds, int w, int l) {
#pragma unroll
    for (int j = 0; j < 2; ++j) {
        int gi = j * 8 + w;
        int base8;
        if constexpr (SEL == 0)      base8 = (gi & 7) + (gi >> 3) * 16;
        else if constexpr (SEL == 1) base8 = (gi & 7) + (gi >> 3) * 16 + 8;
        else if constexpr (SEL == 2) base8 = (gi & 3) + (gi >> 2) * 8;
        else                         base8 = (gi & 3) + (gi >> 2) * 8 + 4;
        int row  = base8 * 8 + (l >> 3);
        int scol = ((l & 7) ^ (l >> 3)) * 8;
        __builtin_amdgcn_global_load_lds(
            (const __attribute__((address_space(1))) unsigned int*)
                (G + (size_t)(growbase + row) * KDIM + kbase + scol),
            (__attribute__((address_space(3))) unsigned int*)(lds + base8 * 512),
            16, 0, 0);
    }
}
#define ST_AE 0
#define ST_AO 1
#define ST_BE 2
#define ST_BO 3

template <int MH, int NH>
__device__ __forceinline__ void do_mfma(f32x4 (&acc)[8][4], bf16x8 (&af)[4][2],
                                        bf16x8 (&bf)[2][2][2]) {
#pragma unroll
    for (int m = 0; m < 4; ++m)
#pragma unroll
        for (int n = 0; n < 2; ++n)
#pragma unroll
            for (int kk = 0; kk < 2; ++kk)
                acc[MH * 4 + m][NH * 2 + n] =
                    __builtin_amdgcn_mfma_f32_16x16x32_bf16(
                        af[m][kk], bf[NH][n][kk], acc[MH * 4 + m][NH * 2 + n],
                        0, 0, 0);
}

__global__ __launch_bounds__(512, 2) void gemm_bt(const unsigned short* __restrict__ A,
                                                  const unsigned short* __restrict__ Bt,
                                                  float* __restrict__ C) {
    __shared__ unsigned short LDS[4 * 256 * 64];   // 128 KiB
    unsigned short* const as0 = LDS;
    unsigned short* const as1 = LDS + 16384;
    unsigned short* const bs0 = LDS + 32768;
    unsigned short* const bs1 = LDS + 49152;

    const int tid = threadIdx.x;
    const int w = tid >> 6, l = tid & 63;
    const int wr = w >> 2, wc = w & 3;
    const int brow = blockIdx.y * 256, bcol = blockIdx.x * 256;

    const int rl = l & 15, g = l >> 4;
    const int aoff  = (wr * 128 + rl) * 64;
    const int boff  = (wc * 64 + rl) * 64;
    const int k0off = ((g)     ^ (rl & 7)) * 8;
    const int k1off = ((4 + g) ^ (rl & 7)) * 8;

    f32x4 acc[8][4];
#pragma unroll
    for (int m = 0; m < 8; ++m)
#pragma unroll
        for (int n = 0; n < 4; ++n) acc[m][n] = (f32x4){0.f, 0.f, 0.f, 0.f};

    bf16x8 af[4][2];
    bf16x8 bf[2][2][2];

#define RD_A(pa, mh)                                                          \
    _Pragma("unroll") for (int m = 0; m < 4; ++m) {                           \
        af[m][0] = *(const bf16x8*)((pa) + aoff + ((mh) * 64 + m * 16) * 64 + k0off); \
        af[m][1] = *(const bf16x8*)((pa) + aoff + ((mh) * 64 + m * 16) * 64 + k1off); \
    }
#define RD_B(pb, nh)                                                          \
    _Pragma("unroll") for (int n = 0; n < 2; ++n) {                           \
        bf[nh][n][0] = *(const bf16x8*)((pb) + boff + ((nh) * 32 + n * 16) * 64 + k0off); \
        bf[nh][n][1] = *(const bf16x8*)((pb) + boff + ((nh) * 32 + n * 16) * 64 + k1off); \
    }

#define KB(t) ((((t) & (NKT - 1))) * 64)

#define PH_TAIL(MH, NH)                                                       \
    __builtin_amdgcn_s_barrier();                                             \
    asm volatile("s_waitcnt lgkmcnt(0)" ::: "memory");                        \
    __builtin_amdgcn_s_setprio(1);                                            \
    do_mfma<MH, NH>(acc, af, bf);                                             \
    __builtin_amdgcn_s_setprio(0);                                            \
    __builtin_amdgcn_s_barrier();

    // Prologue: T0 (4 parts, buf0) + T1 (Ae,Be,Bo, buf1); keep T1's 3 parts
    // (6 loads) in flight.
    stage_part<ST_AE>(A,  brow, 0,  as0, w, l);
    stage_part<ST_AO>(A,  brow, 0,  as0, w, l);
    stage_part<ST_BE>(Bt, bcol, 0,  bs0, w, l);
    stage_part<ST_BO>(Bt, bcol, 0,  bs0, w, l);
    stage_part<ST_AE>(A,  brow, 64, as1, w, l);
    stage_part<ST_BE>(Bt, bcol, 64, bs1, w, l);
    stage_part<ST_BO>(Bt, bcol, 64, bs1, w, l);
    asm volatile("s_waitcnt vmcnt(6)" ::: "memory");
    __builtin_amdgcn_s_barrier();

    for (int it = 0; it < NKT / 2; ++it) {
        const int t2 = 2 * it;

        // ---- tile t2 (buf0) ----
        // P1: q(0,0); stage (t2+1).Ao -> buf1   [buf1.Ao freed prev P7]
        RD_A(as0, 0); RD_B(bs0, 0);
        stage_part<ST_AO>(A, brow, KB(t2 + 1), as1, w, l);
        PH_TAIL(0, 0)
        // P2: q(0,1); stage (t2+2).Ae -> buf0   [buf0.Ae freed P1]
        RD_B(bs0, 1);
        stage_part<ST_AE>(A, brow, KB(t2 + 2), as0, w, l);
        PH_TAIL(0, 1)
        // P3: q(1,1); stage (t2+2).Be -> buf0   [buf0.Be freed P1]
        RD_A(as0, 1);
        stage_part<ST_BE>(Bt, bcol, KB(t2 + 2), bs0, w, l);
        PH_TAIL(1, 1)
        // P4: q(1,0); stage (t2+2).Bo -> buf0   [buf0.Bo freed P2]
        stage_part<ST_BO>(Bt, bcol, KB(t2 + 2), bs0, w, l);
        asm volatile("s_waitcnt vmcnt(6)" ::: "memory");  // t2+1 landed
        PH_TAIL(1, 0)

        // ---- tile t2+1 (buf1) ----
        // P5: q(0,0); stage (t2+2).Ao -> buf0   [buf0.Ao freed P3]
        RD_A(as1, 0); RD_B(bs1, 0);
        stage_part<ST_AO>(A, brow, KB(t2 + 2), as0, w, l);
        PH_TAIL(0, 0)
        // P6: q(0,1); stage (t2+3).Ae -> buf1   [buf1.Ae freed P5]
        RD_B(bs1, 1);
        stage_part<ST_AE>(A, brow, KB(t2 + 3), as1, w, l);
        PH_TAIL(0, 1)
        // P7: q(1,1); stage (t2+3).Be -> buf1   [buf1.Be freed P5]
        RD_A(as1, 1);
        stage_part<ST_BE>(Bt, bcol, KB(t2 + 3), bs1, w, l);
        PH_TAIL(1, 1)
        // P8: q(1,0); stage (t2+3).Bo -> buf1   [buf1.Bo freed P6]
        stage_part<ST_BO>(Bt, bcol, KB(t2 + 3), bs1, w, l);
        asm volatile("s_waitcnt vmcnt(6)" ::: "memory");  // t2+2 landed
        PH_TAIL(1, 0)
    }

    asm volatile("s_waitcnt vmcnt(0) lgkmcnt(0)" ::: "memory");

    // C/D layout: col = lane&15, row = (lane>>4)*4 + reg
#pragma unroll
    for (int m = 0; m < 8; ++m) {
        int r0 = brow + wr * 128 + m * 16 + (l >> 4) * 4;
#pragma unroll
        for (int n = 0; n < 4; ++n) {
            int c0 = bcol + wc * 64 + n * 16 + rl;
#pragma unroll
            for (int r = 0; r < 4; ++r)
                C[(size_t)(r0 + r) * NDIM + c0] = acc[m][n][r];
        }
    }
#undef RD_A
#undef RD_B
#undef KB
#undef PH_TAIL
}

extern "C" void kernel_launch(void* const* d_in, const int* in_sizes, int n_in,
                              void* d_out, int out_size, void* d_ws, size_t ws_size,
                              hipStream_t stream) {
    const float* x = (const float*)d_in[0];
    float* out = (float*)d_out;

    unsigned short* xb = (unsigned short*)d_ws;                  // 32 MB
    unsigned short* wt = xb + (size_t)MDIM * KDIM;               // 32 MB

    cvt_x_bf16<<<(MDIM * KDIM / 8) / 256, 256, 0, stream>>>(x, xb);
    gen_Wt<<<(NDIM * KDIM / 8) / 256, 256, 0, stream>>>(wt);

    dim3 grid(NDIM / 256, MDIM / 256);
    gemm_bt<<<grid, 512, 0, stream>>>(xb, wt, out);
}

// Round 5
// 134.781 us; speedup vs baseline: 1.5770x; 1.0034x over previous
//
#include <hip/hip_runtime.h>
#include <hip/hip_bf16.h>

// IDST (DST-III, x2) as y = x @ W, W[n][k] = 2*a_n*sin(pi*(n+1)*(2k+1)/(2N)).
// R5: remove the per-phase s_waitcnt lgkmcnt(0) full drain. ds_reads are
// compiler-visible loads -> compiler emits counted lgkmcnt per MFMA, so the
// LDS return time overlaps the MFMA cluster instead of serializing with it.
// Phase boundaries keep compiler-only fences (asm "" memory) + s_barrier.
// Staging schedule/vmcnt(6) identical to R4 (proven correct).

#define MDIM 4096
#define NDIM 4096
#define KDIM 4096
#define NKT  (KDIM / 64)

using f32x4  = __attribute__((ext_vector_type(4))) float;
using bf16x8 = __attribute__((ext_vector_type(8))) short;

__device__ inline unsigned short f2bf(float f) {
    union { float f; unsigned int u; } v; v.f = f;
    unsigned int r = (v.u + 0x7fffu + ((v.u >> 16) & 1u)) >> 16; // RNE
    return (unsigned short)r;
}

__global__ __launch_bounds__(256) void cvt_x_bf16(const float* __restrict__ x,
                                                  unsigned short* __restrict__ o) {
    int idx = blockIdx.x * 256 + threadIdx.x;
    const float4* xin = (const float4*)x;
    float4 a = xin[2 * idx];
    float4 b = xin[2 * idx + 1];
    union { unsigned short u[8]; uint4 v; } r;
    r.u[0] = f2bf(a.x); r.u[1] = f2bf(a.y); r.u[2] = f2bf(a.z); r.u[3] = f2bf(a.w);
    r.u[4] = f2bf(b.x); r.u[5] = f2bf(b.y); r.u[6] = f2bf(b.z); r.u[7] = f2bf(b.w);
    ((uint4*)o)[idx] = r.v;
}

__global__ __launch_bounds__(256) void gen_Wt(unsigned short* __restrict__ Wt) {
    int idx = blockIdx.x * 256 + threadIdx.x;
    int k  = idx >> 9;
    int n0 = (idx & 511) * 8;
    unsigned int tk = 2u * (unsigned)k + 1u;
    union { unsigned short u[8]; uint4 v; } r;
#pragma unroll
    for (int t = 0; t < 8; ++t) {
        unsigned int n = (unsigned)(n0 + t);
        unsigned int m = ((n + 1u) * tk) & 16383u;
        float ang = (float)m * 3.8349519697e-4f;   // pi/8192
        float s = __sinf(ang);
        float scale = (n == (unsigned)(KDIM - 1)) ? 1.0f : 2.0f;
        r.u[t] = f2bf(s * scale);
    }
    ((uint4*)Wt)[idx] = r.v;
}

// Stage one quarter-tile (64 rows as 16 x 8-row groups), 2 gload_lds/thread.
//   Ae: groups {0-7,16-23}   (rows {0-63,128-191})
//   Ao: +8                   (rows {64-127,192-255})
//   Be: {0-3,8-11,16-19,24-27} (rows {0-31,64-95,128-159,192-223})
//   Bo: +4
// Linear LDS dest per 8-row group; global source slot pre-swizzled (^row&7).
template <int SEL>
__device__ __forceinline__ void stage_part(const unsigned short* __restrict__ G,
                                           int growbase, int kbase,
                                           unsigned short* lds, int w, int l) {
#pragma unroll
    for (int j = 0; j < 2; ++j) {
        int gi = j * 8 + w;
        int base8;
        if constexpr (SEL == 0)      base8 = (gi & 7) + (gi >> 3) * 16;
        else if constexpr (SEL == 1) base8 = (gi & 7) + (gi >> 3) * 16 + 8;
        else if constexpr (SEL == 2) base8 = (gi & 3) + (gi >> 2) * 8;
        else                         base8 = (gi & 3) + (gi >> 2) * 8 + 4;
        int row  = base8 * 8 + (l >> 3);
        int scol = ((l & 7) ^ (l >> 3)) * 8;
        __builtin_amdgcn_global_load_lds(
            (const __attribute__((address_space(1))) unsigned int*)
                (G + (size_t)(growbase + row) * KDIM + kbase + scol),
            (__attribute__((address_space(3))) unsigned int*)(lds + base8 * 512),
            16, 0, 0);
    }
}
#define ST_AE 0
#define ST_AO 1
#define ST_BE 2
#define ST_BO 3

template <int MH, int NH>
__device__ __forceinline__ void do_mfma(f32x4 (&acc)[8][4], bf16x8 (&af)[4][2],
                                        bf16x8 (&bf)[2][2][2]) {
#pragma unroll
    for (int m = 0; m < 4; ++m)
#pragma unroll
        for (int n = 0; n < 2; ++n)
#pragma unroll
            for (int kk = 0; kk < 2; ++kk)
                acc[MH * 4 + m][NH * 2 + n] =
                    __builtin_amdgcn_mfma_f32_16x16x32_bf16(
                        af[m][kk], bf[NH][n][kk], acc[MH * 4 + m][NH * 2 + n],
                        0, 0, 0);
}

__global__ __launch_bounds__(512, 2) void gemm_bt(const unsigned short* __restrict__ A,
                                                  const unsigned short* __restrict__ Bt,
                                                  float* __restrict__ C) {
    __shared__ unsigned short LDS[4 * 256 * 64];   // 128 KiB
    unsigned short* const as0 = LDS;
    unsigned short* const as1 = LDS + 16384;
    unsigned short* const bs0 = LDS + 32768;
    unsigned short* const bs1 = LDS + 49152;

    const int tid = threadIdx.x;
    const int w = tid >> 6, l = tid & 63;
    const int wr = w >> 2, wc = w & 3;
    const int brow = blockIdx.y * 256, bcol = blockIdx.x * 256;

    const int rl = l & 15, g = l >> 4;
    const int aoff  = (wr * 128 + rl) * 64;
    const int boff  = (wc * 64 + rl) * 64;
    const int k0off = ((g)     ^ (rl & 7)) * 8;
    const int k1off = ((4 + g) ^ (rl & 7)) * 8;

    f32x4 acc[8][4];
#pragma unroll
    for (int m = 0; m < 8; ++m)
#pragma unroll
        for (int n = 0; n < 4; ++n) acc[m][n] = (f32x4){0.f, 0.f, 0.f, 0.f};

    bf16x8 af[4][2];
    bf16x8 bf[2][2][2];

#define RD_A(pa, mh)                                                          \
    _Pragma("unroll") for (int m = 0; m < 4; ++m) {                           \
        af[m][0] = *(const bf16x8*)((pa) + aoff + ((mh) * 64 + m * 16) * 64 + k0off); \
        af[m][1] = *(const bf16x8*)((pa) + aoff + ((mh) * 64 + m * 16) * 64 + k1off); \
    }
#define RD_B(pb, nh)                                                          \
    _Pragma("unroll") for (int n = 0; n < 2; ++n) {                           \
        bf[nh][n][0] = *(const bf16x8*)((pb) + boff + ((nh) * 32 + n * 16) * 64 + k0off); \
        bf[nh][n][1] = *(const bf16x8*)((pb) + boff + ((nh) * 32 + n * 16) * 64 + k1off); \
    }

#define KB(t) ((((t) & (NKT - 1))) * 64)

// No lgkmcnt(0) drain: compiler-tracked ds_read->MFMA deps give counted waits,
// so LDS returns overlap the MFMA cluster. Compiler-only fences pin memory ops
// to their phase.
#define PH_TAIL(MH, NH)                                                       \
    asm volatile("" ::: "memory");                                            \
    __builtin_amdgcn_s_barrier();                                             \
    __builtin_amdgcn_s_setprio(1);                                            \
    do_mfma<MH, NH>(acc, af, bf);                                             \
    __builtin_amdgcn_s_setprio(0);                                            \
    asm volatile("" ::: "memory");                                            \
    __builtin_amdgcn_s_barrier();

    // Prologue: T0 (4 parts, buf0) + T1 (Ae,Be,Bo, buf1); 3 parts in flight.
    stage_part<ST_AE>(A,  brow, 0,  as0, w, l);
    stage_part<ST_AO>(A,  brow, 0,  as0, w, l);
    stage_part<ST_BE>(Bt, bcol, 0,  bs0, w, l);
    stage_part<ST_BO>(Bt, bcol, 0,  bs0, w, l);
    stage_part<ST_AE>(A,  brow, 64, as1, w, l);
    stage_part<ST_BE>(Bt, bcol, 64, bs1, w, l);
    stage_part<ST_BO>(Bt, bcol, 64, bs1, w, l);
    asm volatile("s_waitcnt vmcnt(6)" ::: "memory");
    __builtin_amdgcn_s_barrier();

    for (int it = 0; it < NKT / 2; ++it) {
        const int t2 = 2 * it;

        // ---- tile t2 (buf0) ----
        // P1: q(0,0); stage (t2+1).Ao -> buf1   [buf1.Ao freed prev P7]
        RD_A(as0, 0); RD_B(bs0, 0);
        stage_part<ST_AO>(A, brow, KB(t2 + 1), as1, w, l);
        PH_TAIL(0, 0)
        // P2: q(0,1); stage (t2+2).Ae -> buf0   [buf0.Ae freed P1]
        RD_B(bs0, 1);
        stage_part<ST_AE>(A, brow, KB(t2 + 2), as0, w, l);
        PH_TAIL(0, 1)
        // P3: q(1,1); stage (t2+2).Be -> buf0   [buf0.Be freed P1]
        RD_A(as0, 1);
        stage_part<ST_BE>(Bt, bcol, KB(t2 + 2), bs0, w, l);
        PH_TAIL(1, 1)
        // P4: q(1,0); stage (t2+2).Bo -> buf0   [buf0.Bo freed P2]
        stage_part<ST_BO>(Bt, bcol, KB(t2 + 2), bs0, w, l);
        asm volatile("s_waitcnt vmcnt(6)" ::: "memory");  // t2+1 landed
        PH_TAIL(1, 0)

        // ---- tile t2+1 (buf1) ----
        // P5: q(0,0); stage (t2+2).Ao -> buf0   [buf0.Ao freed P3]
        RD_A(as1, 0); RD_B(bs1, 0);
        stage_part<ST_AO>(A, brow, KB(t2 + 2), as0, w, l);
        PH_TAIL(0, 0)
        // P6: q(0,1); stage (t2+3).Ae -> buf1   [buf1.Ae freed P5]
        RD_B(bs1, 1);
        stage_part<ST_AE>(A, brow, KB(t2 + 3), as1, w, l);
        PH_TAIL(0, 1)
        // P7: q(1,1); stage (t2+3).Be -> buf1   [buf1.Be freed P5]
        RD_A(as1, 1);
        stage_part<ST_BE>(Bt, bcol, KB(t2 + 3), bs1, w, l);
        PH_TAIL(1, 1)
        // P8: q(1,0); stage (t2+3).Bo -> buf1   [buf1.Bo freed P6]
        stage_part<ST_BO>(Bt, bcol, KB(t2 + 3), bs1, w, l);
        asm volatile("s_waitcnt vmcnt(6)" ::: "memory");  // t2+2 landed
        PH_TAIL(1, 0)
    }

    asm volatile("s_waitcnt vmcnt(0) lgkmcnt(0)" ::: "memory");

    // C/D layout: col = lane&15, row = (lane>>4)*4 + reg
#pragma unroll
    for (int m = 0; m < 8; ++m) {
        int r0 = brow + wr * 128 + m * 16 + (l >> 4) * 4;
#pragma unroll
        for (int n = 0; n < 4; ++n) {
            int c0 = bcol + wc * 64 + n * 16 + rl;
#pragma unroll
            for (int r = 0; r < 4; ++r)
                C[(size_t)(r0 + r) * NDIM + c0] = acc[m][n][r];
        }
    }
#undef RD_A
#undef RD_B
#undef KB
#undef PH_TAIL
}

extern "C" void kernel_launch(void* const* d_in, const int* in_sizes, int n_in,
                              void* d_out, int out_size, void* d_ws, size_t ws_size,
                              hipStream_t stream) {
    const float* x = (const float*)d_in[0];
    float* out = (float*)d_out;

    unsigned short* xb = (unsigned short*)d_ws;                  // 32 MB
    unsigned short* wt = xb + (size_t)MDIM * KDIM;               // 32 MB

    cvt_x_bf16<<<(MDIM * KDIM / 8) / 256, 256, 0, stream>>>(x, xb);
    gen_Wt<<<(NDIM * KDIM / 8) / 256, 256, 0, stream>>>(wt);

    dim3 grid(NDIM / 256, MDIM / 256);
    gemm_bt<<<grid, 512, 0, stream>>>(xb, wt, out);
}

// Round 6
// 133.538 us; speedup vs baseline: 1.5917x; 1.0093x over previous
//
#include <hip/hip_runtime.h>
#include <hip/hip_bf16.h>

// IDST (DST-III, x2) as y = x @ W, W[n][k] = 2*a_n*sin(pi*(n+1)*(2k+1)/(2N)).
// R6: single barrier per phase (removed the read->MFMA barrier). Reads and
// MFMAs of different waves now share the inter-barrier window, so the LDS
// pipe (~2.3k cyc/tile) overlaps the matrix pipe (~2.5k cyc/tile) instead of
// serializing (R3-R5 measured 4526 cyc/tile = exact sum). vmcnt moved after
// the MFMA cluster. WAR safety: a wave at the end-phase barrier has issued
// its MFMAs, which consumed its reads; every stage targets a region
// last-read >=1 barrier earlier (ledger in comments below).

#define MDIM 4096
#define NDIM 4096
#define KDIM 4096
#define NKT  (KDIM / 64)

using f32x4  = __attribute__((ext_vector_type(4))) float;
using bf16x8 = __attribute__((ext_vector_type(8))) short;

__device__ inline unsigned short f2bf(float f) {
    union { float f; unsigned int u; } v; v.f = f;
    unsigned int r = (v.u + 0x7fffu + ((v.u >> 16) & 1u)) >> 16; // RNE
    return (unsigned short)r;
}

__global__ __launch_bounds__(256) void cvt_x_bf16(const float* __restrict__ x,
                                                  unsigned short* __restrict__ o) {
    int idx = blockIdx.x * 256 + threadIdx.x;
    const float4* xin = (const float4*)x;
    float4 a = xin[2 * idx];
    float4 b = xin[2 * idx + 1];
    union { unsigned short u[8]; uint4 v; } r;
    r.u[0] = f2bf(a.x); r.u[1] = f2bf(a.y); r.u[2] = f2bf(a.z); r.u[3] = f2bf(a.w);
    r.u[4] = f2bf(b.x); r.u[5] = f2bf(b.y); r.u[6] = f2bf(b.z); r.u[7] = f2bf(b.w);
    ((uint4*)o)[idx] = r.v;
}

__global__ __launch_bounds__(256) void gen_Wt(unsigned short* __restrict__ Wt) {
    int idx = blockIdx.x * 256 + threadIdx.x;
    int k  = idx >> 9;
    int n0 = (idx & 511) * 8;
    unsigned int tk = 2u * (unsigned)k + 1u;
    union { unsigned short u[8]; uint4 v; } r;
#pragma unroll
    for (int t = 0; t < 8; ++t) {
        unsigned int n = (unsigned)(n0 + t);
        unsigned int m = ((n + 1u) * tk) & 16383u;
        float ang = (float)m * 3.8349519697e-4f;   // pi/8192
        float s = __sinf(ang);
        float scale = (n == (unsigned)(KDIM - 1)) ? 1.0f : 2.0f;
        r.u[t] = f2bf(s * scale);
    }
    ((uint4*)Wt)[idx] = r.v;
}

// Stage one quarter-tile (64 rows as 16 x 8-row groups), 2 gload_lds/thread.
//   Ae: groups {0-7,16-23}     rows {0-63,128-191}
//   Ao: +8                     rows {64-127,192-255}
//   Be: {0-3,8-11,16-19,24-27} rows {0-31,64-95,128-159,192-223}
//   Bo: +4
// Linear LDS dest per 8-row group; global source slot pre-swizzled (^row&7).
template <int SEL>
__device__ __forceinline__ void stage_part(const unsigned short* __restrict__ G,
                                           int growbase, int kbase,
                                           unsigned short* lds, int w, int l) {
#pragma unroll
    for (int j = 0; j < 2; ++j) {
        int gi = j * 8 + w;
        int base8;
        if constexpr (SEL == 0)      base8 = (gi & 7) + (gi >> 3) * 16;
        else if constexpr (SEL == 1) base8 = (gi & 7) + (gi >> 3) * 16 + 8;
        else if constexpr (SEL == 2) base8 = (gi & 3) + (gi >> 2) * 8;
        else                         base8 = (gi & 3) + (gi >> 2) * 8 + 4;
        int row  = base8 * 8 + (l >> 3);
        int scol = ((l & 7) ^ (l >> 3)) * 8;
        __builtin_amdgcn_global_load_lds(
            (const __attribute__((address_space(1))) unsigned int*)
                (G + (size_t)(growbase + row) * KDIM + kbase + scol),
            (__attribute__((address_space(3))) unsigned int*)(lds + base8 * 512),
            16, 0, 0);
    }
}
#define ST_AE 0
#define ST_AO 1
#define ST_BE 2
#define ST_BO 3

template <int MH, int NH>
__device__ __forceinline__ void do_mfma(f32x4 (&acc)[8][4], bf16x8 (&af)[4][2],
                                        bf16x8 (&bf)[2][2][2]) {
#pragma unroll
    for (int m = 0; m < 4; ++m)
#pragma unroll
        for (int n = 0; n < 2; ++n)
#pragma unroll
            for (int kk = 0; kk < 2; ++kk)
                acc[MH * 4 + m][NH * 2 + n] =
                    __builtin_amdgcn_mfma_f32_16x16x32_bf16(
                        af[m][kk], bf[NH][n][kk], acc[MH * 4 + m][NH * 2 + n],
                        0, 0, 0);
}

__global__ __launch_bounds__(512, 2) void gemm_bt(const unsigned short* __restrict__ A,
                                                  const unsigned short* __restrict__ Bt,
                                                  float* __restrict__ C) {
    __shared__ unsigned short LDS[4 * 256 * 64];   // 128 KiB
    unsigned short* const as0 = LDS;
    unsigned short* const as1 = LDS + 16384;
    unsigned short* const bs0 = LDS + 32768;
    unsigned short* const bs1 = LDS + 49152;

    const int tid = threadIdx.x;
    const int w = tid >> 6, l = tid & 63;
    const int wr = w >> 2, wc = w & 3;
    const int brow = blockIdx.y * 256, bcol = blockIdx.x * 256;

    const int rl = l & 15, g = l >> 4;
    const int aoff  = (wr * 128 + rl) * 64;
    const int boff  = (wc * 64 + rl) * 64;
    const int k0off = ((g)     ^ (rl & 7)) * 8;
    const int k1off = ((4 + g) ^ (rl & 7)) * 8;

    f32x4 acc[8][4];
#pragma unroll
    for (int m = 0; m < 8; ++m)
#pragma unroll
        for (int n = 0; n < 4; ++n) acc[m][n] = (f32x4){0.f, 0.f, 0.f, 0.f};

    bf16x8 af[4][2];
    bf16x8 bf[2][2][2];

#define RD_A(pa, mh)                                                          \
    _Pragma("unroll") for (int m = 0; m < 4; ++m) {                           \
        af[m][0] = *(const bf16x8*)((pa) + aoff + ((mh) * 64 + m * 16) * 64 + k0off); \
        af[m][1] = *(const bf16x8*)((pa) + aoff + ((mh) * 64 + m * 16) * 64 + k1off); \
    }
#define RD_B(pb, nh)                                                          \
    _Pragma("unroll") for (int n = 0; n < 2; ++n) {                           \
        bf[nh][n][0] = *(const bf16x8*)((pb) + boff + ((nh) * 32 + n * 16) * 64 + k0off); \
        bf[nh][n][1] = *(const bf16x8*)((pb) + boff + ((nh) * 32 + n * 16) * 64 + k1off); \
    }

#define KB(t) ((((t) & (NKT - 1))) * 64)

// One barrier per phase: MFMA cluster, compiler fence, barrier. Reads of the
// NEXT phase stay after the barrier (fence pins memory ops); read->MFMA
// ordering within a wave is register dependence (counted lgkm by compiler).
#define PH_END(MH, NH)                                                        \
    __builtin_amdgcn_s_setprio(1);                                            \
    do_mfma<MH, NH>(acc, af, bf);                                             \
    __builtin_amdgcn_s_setprio(0);                                            \
    asm volatile("" ::: "memory");                                            \
    __builtin_amdgcn_s_barrier();

#define PH_END_VM(MH, NH)                                                     \
    __builtin_amdgcn_s_setprio(1);                                            \
    do_mfma<MH, NH>(acc, af, bf);                                             \
    __builtin_amdgcn_s_setprio(0);                                            \
    asm volatile("s_waitcnt vmcnt(6)" ::: "memory");                          \
    __builtin_amdgcn_s_barrier();

    // Prologue: T0 (4 parts, buf0) + T1 (Ae,Be,Bo, buf1); drain T0, keep
    // T1's 3 parts (6 loads) in flight.
    stage_part<ST_AE>(A,  brow, 0,  as0, w, l);
    stage_part<ST_AO>(A,  brow, 0,  as0, w, l);
    stage_part<ST_BE>(Bt, bcol, 0,  bs0, w, l);
    stage_part<ST_BO>(Bt, bcol, 0,  bs0, w, l);
    stage_part<ST_AE>(A,  brow, 64, as1, w, l);
    stage_part<ST_BE>(Bt, bcol, 64, bs1, w, l);
    stage_part<ST_BO>(Bt, bcol, 64, bs1, w, l);
    asm volatile("s_waitcnt vmcnt(6)" ::: "memory");
    __builtin_amdgcn_s_barrier();

    for (int it = 0; it < NKT / 2; ++it) {
        const int t2 = 2 * it;

        // ---- tile t2 (buf0) ----
        // P1: q(0,0); stage (t2+1).Ao -> buf1.Ao [last read prev P7]
        RD_A(as0, 0); RD_B(bs0, 0);
        stage_part<ST_AO>(A, brow, KB(t2 + 1), as1, w, l);
        PH_END(0, 0)
        // P2: q(0,1); stage (t2+2).Ae -> buf0.Ae [last read P1]
        RD_B(bs0, 1);
        stage_part<ST_AE>(A, brow, KB(t2 + 2), as0, w, l);
        PH_END(0, 1)
        // P3: q(1,1); stage (t2+2).Be -> buf0.Be [last read P1]
        RD_A(as0, 1);
        stage_part<ST_BE>(Bt, bcol, KB(t2 + 2), bs0, w, l);
        PH_END(1, 1)
        // P4: q(1,0); stage (t2+2).Bo -> buf0.Bo [last read P2];
        //     vmcnt(6) drains prev-P6..P1 stages = all of t2+1
        stage_part<ST_BO>(Bt, bcol, KB(t2 + 2), bs0, w, l);
        PH_END_VM(1, 0)

        // ---- tile t2+1 (buf1) ----
        // P5: q(0,0); stage (t2+2).Ao -> buf0.Ao [last read P3]
        RD_A(as1, 0); RD_B(bs1, 0);
        stage_part<ST_AO>(A, brow, KB(t2 + 2), as0, w, l);
        PH_END(0, 0)
        // P6: q(0,1); stage (t2+3).Ae -> buf1.Ae [last read P5]
        RD_B(bs1, 1);
        stage_part<ST_AE>(A, brow, KB(t2 + 3), as1, w, l);
        PH_END(0, 1)
        // P7: q(1,1); stage (t2+3).Be -> buf1.Be [last read P5]
        RD_A(as1, 1);
        stage_part<ST_BE>(Bt, bcol, KB(t2 + 3), bs1, w, l);
        PH_END(1, 1)
        // P8: q(1,0); stage (t2+3).Bo -> buf1.Bo [last read P6];
        //     vmcnt(6) drains P2..P5 stages = all of t2+2
        stage_part<ST_BO>(Bt, bcol, KB(t2 + 3), bs1, w, l);
        PH_END_VM(1, 0)
    }

    asm volatile("s_waitcnt vmcnt(0) lgkmcnt(0)" ::: "memory");

    // C/D layout: col = lane&15, row = (lane>>4)*4 + reg
#pragma unroll
    for (int m = 0; m < 8; ++m) {
        int r0 = brow + wr * 128 + m * 16 + (l >> 4) * 4;
#pragma unroll
        for (int n = 0; n < 4; ++n) {
            int c0 = bcol + wc * 64 + n * 16 + rl;
#pragma unroll
            for (int r = 0; r < 4; ++r)
                C[(size_t)(r0 + r) * NDIM + c0] = acc[m][n][r];
        }
    }
#undef RD_A
#undef RD_B
#undef KB
#undef PH_END
#undef PH_END_VM
}

extern "C" void kernel_launch(void* const* d_in, const int* in_sizes, int n_in,
                              void* d_out, int out_size, void* d_ws, size_t ws_size,
                              hipStream_t stream) {
    const float* x = (const float*)d_in[0];
    float* out = (float*)d_out;

    unsigned short* xb = (unsigned short*)d_ws;                  // 32 MB
    unsigned short* wt = xb + (size_t)MDIM * KDIM;               // 32 MB

    cvt_x_bf16<<<(MDIM * KDIM / 8) / 256, 256, 0, stream>>>(x, xb);
    gen_Wt<<<(NDIM * KDIM / 8) / 256, 256, 0, stream>>>(wt);

    dim3 grid(NDIM / 256, MDIM / 256);
    gemm_bt<<<grid, 512, 0, stream>>>(xb, wt, out);
}